// Round 1
// baseline (216.648 us; speedup 1.0000x reference)
//
#include <hip/hip_runtime.h>
#include <stdint.h>

#define Bn 2048
#define Dn 1024
#define Hn 2048
#define On 512
#define En 8

typedef __bf16 bf16x8 __attribute__((ext_vector_type(8)));
typedef float f32x4 __attribute__((ext_vector_type(4)));
typedef unsigned short ushort_t;
typedef ushort_t ushort8 __attribute__((ext_vector_type(8)));

__device__ __forceinline__ ushort_t f2bf(float v) {
  union { float f; uint32_t u; } a; a.f = v;
  uint32_t u = a.u;
  return (ushort_t)((u + 0x7fffu + ((u >> 16) & 1u)) >> 16);  // RNE, finite inputs
}

__device__ __forceinline__ void gload16(const void* g, void* l) {
  __builtin_amdgcn_global_load_lds((const uint32_t*)g, (uint32_t*)l, 16, 0, 0);
}

// ---------------- init: zero counts/cursors every launch (determinism) ----------------
__global__ void init_kernel(int* counts, int* cursors) {
  int t = threadIdx.x;
  if (t < En) { counts[t] = 0; cursors[t] = 0; }
}

// ---------------- cast x f32 -> bf16 ----------------
__global__ void cast_x_kernel(const float* __restrict__ in, ushort_t* __restrict__ out, int n8) {
  int i = blockIdx.x * 256 + threadIdx.x;
  if (i >= n8) return;
  const float4* p = (const float4*)in;
  float4 a = p[2 * i], b = p[2 * i + 1];
  ushort8 r;
  r[0] = f2bf(a.x); r[1] = f2bf(a.y); r[2] = f2bf(a.z); r[3] = f2bf(a.w);
  r[4] = f2bf(b.x); r[5] = f2bf(b.y); r[6] = f2bf(b.z); r[7] = f2bf(b.w);
  *(ushort8*)(out + (size_t)8 * i) = r;
}

// ------- transpose+cast: in [z][R][C] f32 -> out [z][C][R] bf16 (32x32 LDS tiles) -------
__global__ void tcast_kernel(const float* __restrict__ in, ushort_t* __restrict__ out, int R, int C) {
  __shared__ float tile[32][33];
  int z = blockIdx.z;
  const float* inp = in + (size_t)z * R * C;
  ushort_t* outp = out + (size_t)z * R * C;
  int r0 = blockIdx.y * 32, c0 = blockIdx.x * 32;
  int tx = threadIdx.x, ty = threadIdx.y;
#pragma unroll
  for (int j = 0; j < 32; j += 8)
    tile[ty + j][tx] = inp[(size_t)(r0 + ty + j) * C + (c0 + tx)];
  __syncthreads();
#pragma unroll
  for (int j = 0; j < 32; j += 8)
    outp[(size_t)(c0 + ty + j) * R + (r0 + tx)] = f2bf(tile[tx][ty + j]);
}

// ---------------- gating: logits = x @ w_gate, top-2, softmax over 2 ----------------
__global__ void gating_kernel(const float* __restrict__ x, const float* __restrict__ wg,
                              int* __restrict__ top_idx, float* __restrict__ gates,
                              int* __restrict__ counts) {
  int w = threadIdx.x >> 6, lane = threadIdx.x & 63;
  int b = blockIdx.x * 4 + w;
  const float* xr = x + (size_t)b * Dn;
  float acc[En];
#pragma unroll
  for (int e = 0; e < En; e++) acc[e] = 0.f;
  for (int d = lane; d < Dn; d += 64) {
    float xv = xr[d];
    const float* wr_ = wg + (size_t)d * En;
#pragma unroll
    for (int e = 0; e < En; e++) acc[e] += xv * wr_[e];
  }
#pragma unroll
  for (int off = 32; off; off >>= 1) {
#pragma unroll
    for (int e = 0; e < En; e++) acc[e] += __shfl_down(acc[e], off);
  }
  if (lane == 0) {
    float best = -1e30f, second = -1e30f; int bi = 0, si = 0;
#pragma unroll
    for (int e = 0; e < En; e++) {
      float l = acc[e];
      if (l > best) { second = best; si = bi; best = l; bi = e; }
      else if (l > second) { second = l; si = e; }
    }
    float e1 = expf(second - best);
    float inv = 1.f / (1.f + e1);
    top_idx[2 * b] = bi; top_idx[2 * b + 1] = si;
    gates[2 * b] = inv;  gates[2 * b + 1] = e1 * inv;
    atomicAdd(&counts[bi], 1);
    atomicAdd(&counts[si], 1);
  }
}

// ---------------- offsets (exclusive prefix over 8 counts) ----------------
__global__ void offsets_kernel(const int* counts, int* offsets, int* cursors) {
  if (threadIdx.x == 0) {
    int s = 0;
    for (int e = 0; e < En; e++) { offsets[e] = s; s += counts[e]; }
  }
  if (threadIdx.x < En) cursors[threadIdx.x] = 0;
}

// ---------------- assign rows to compact slots ----------------
__global__ void assign_kernel(const int* __restrict__ top_idx, const int* __restrict__ offsets,
                              int* cursors, int* __restrict__ s2r, int* __restrict__ r2s) {
  int b = blockIdx.x * 256 + threadIdx.x;
  if (b >= Bn) return;
#pragma unroll
  for (int k = 0; k < 2; k++) {
    int e = top_idx[2 * b + k];
    int pos = atomicAdd(&cursors[e], 1);
    int slot = offsets[e] + pos;
    s2r[slot] = b;
    r2s[2 * b + k] = slot;
  }
}

// ---------------- grouped GEMM: 128x128x64 tile, 4 waves, mfma 16x16x32 bf16 ----------------
// A [rows][K] bf16 (gathered via s2r for fc1), WT [E][N][K] bf16, bias [E][N] f32.
// FC1: out = bf16(gelu(acc+bias)) -> outH[slot][N];  else: out f32 -> outL[slot][N]
template <bool GATHER, bool FC1, int N, int K>
__global__ __launch_bounds__(256, 2) void moe_gemm_kernel(
    const ushort_t* __restrict__ A, const ushort_t* __restrict__ WT,
    const float* __restrict__ bias, const int* __restrict__ offsets,
    const int* __restrict__ counts, const int* __restrict__ s2r,
    ushort_t* __restrict__ outH, float* __restrict__ outL) {
  int e = blockIdx.z;
  int cnt = counts[e];
  int rb = blockIdx.y;
  if (rb * 128 >= cnt) return;
  int base = offsets[e];
  int nb = blockIdx.x * 128;
  __shared__ __align__(16) ushort_t As[128 * 64];
  __shared__ __align__(16) ushort_t Bs[128 * 64];
  int t = threadIdx.x;
  int lane = t & 63, w = t >> 6;
  int wr = w >> 1, wc = w & 1;

  // gathered A row base pointers (4 stage-iters per thread; rows fixed across K)
  const ushort_t* aptr[4];
#pragma unroll
  for (int i = 0; i < 4; i++) {
    int lr = rb * 128 + i * 32 + (t >> 3);
    int lrc = lr < cnt ? lr : (cnt - 1);
    int slot = base + lrc;
    int row = GATHER ? s2r[slot] : slot;
    aptr[i] = A + (size_t)row * K + (t & 7) * 8;
  }
  const ushort_t* bptr = WT + ((size_t)e * N + nb + (t >> 3)) * K + (t & 7) * 8;

  f32x4 zero = {0.f, 0.f, 0.f, 0.f};
  f32x4 acc[4][4];
#pragma unroll
  for (int m = 0; m < 4; m++)
#pragma unroll
    for (int n = 0; n < 4; n++) acc[m][n] = zero;

  int arow = wr * 64 + (lane & 15);
  int brow = wc * 64 + (lane & 15);
  int kg = (lane >> 4) * 8;

  for (int kt = 0; kt < K; kt += 64) {
#pragma unroll
    for (int i = 0; i < 4; i++) {
      gload16(aptr[i] + kt, &As[i * 2048 + t * 8]);
      gload16(bptr + (size_t)i * 32 * K + kt, &Bs[i * 2048 + t * 8]);
    }
    __syncthreads();  // drains vmcnt before LDS reads
#pragma unroll
    for (int kk = 0; kk < 64; kk += 32) {
      bf16x8 af[4], bfr[4];
#pragma unroll
      for (int m = 0; m < 4; m++) af[m] = *(const bf16x8*)&As[(arow + m * 16) * 64 + kk + kg];
#pragma unroll
      for (int n = 0; n < 4; n++) bfr[n] = *(const bf16x8*)&Bs[(brow + n * 16) * 64 + kk + kg];
#pragma unroll
      for (int m = 0; m < 4; m++)
#pragma unroll
        for (int n = 0; n < 4; n++)
          acc[m][n] = __builtin_amdgcn_mfma_f32_16x16x32_bf16(af[m], bfr[n], acc[m][n], 0, 0, 0);
    }
    __syncthreads();  // protect LDS before next stage
  }

  // epilogue: D layout col=lane&15, row=(lane>>4)*4+i
  int lr0 = rb * 128 + wr * 64;
#pragma unroll
  for (int m = 0; m < 4; m++) {
#pragma unroll
    for (int i = 0; i < 4; i++) {
      int lr = lr0 + m * 16 + (lane >> 4) * 4 + i;
      if (lr < cnt) {
        int slot = base + lr;
#pragma unroll
        for (int n = 0; n < 4; n++) {
          int col = nb + wc * 64 + n * 16 + (lane & 15);
          float v = acc[m][n][i] + bias[e * N + col];
          if (FC1) {
            float g = 0.5f * v * (1.0f + erff(v * 0.70710678118654752f));
            outH[(size_t)slot * N + col] = f2bf(g);
          } else {
            outL[(size_t)slot * N + col] = v;
          }
        }
      }
    }
  }
}

// ---------------- combine: per-row logsoftmax over O=512 for 2 slots, weighted sum ----------------
__device__ __forceinline__ float blk_reduce(float v, bool ismax) {
  __shared__ float sbuf[4];
  int lane = threadIdx.x & 63, w = threadIdx.x >> 6;
#pragma unroll
  for (int off = 32; off; off >>= 1) {
    float o = __shfl_down(v, off);
    v = ismax ? fmaxf(v, o) : (v + o);
  }
  __syncthreads();
  if (lane == 0) sbuf[w] = v;
  __syncthreads();
  float r = sbuf[0];
#pragma unroll
  for (int i = 1; i < 4; i++) r = ismax ? fmaxf(r, sbuf[i]) : (r + sbuf[i]);
  return r;
}

__global__ void combine_kernel(const float* __restrict__ l2, const int* __restrict__ r2s,
                               const float* __restrict__ gates, float* __restrict__ out) {
  int b = blockIdx.x, t = threadIdx.x;
  float c0 = 0.f, c1 = 0.f;
#pragma unroll
  for (int k = 0; k < 2; k++) {
    int slot = r2s[2 * b + k];
    float g = gates[2 * b + k];
    const float* lp = l2 + (size_t)slot * On;
    float v0 = lp[t], v1 = lp[t + 256];
    float m = blk_reduce(fmaxf(v0, v1), true);
    float s = blk_reduce(expf(v0 - m) + expf(v1 - m), false);
    float lse = m + logf(s);
    c0 += g * expf(v0 - lse);
    c1 += g * expf(v1 - lse);
  }
  const float EPSv = 2.220446049250313e-16f;  // np.finfo(float64).eps
  out[(size_t)b * On + t] = logf(fmaxf(c0, EPSv));
  out[(size_t)b * On + t + 256] = logf(fmaxf(c1, EPSv));
}

extern "C" void kernel_launch(void* const* d_in, const int* in_sizes, int n_in,
                              void* d_out, int out_size, void* d_ws, size_t ws_size,
                              hipStream_t stream) {
  const float* x = (const float*)d_in[0];
  const float* wgate = (const float*)d_in[1];
  const float* fc1w = (const float*)d_in[2];
  const float* fc1b = (const float*)d_in[3];
  const float* fc2w = (const float*)d_in[4];
  const float* fc2b = (const float*)d_in[5];
  float* out = (float*)d_out;

  char* ws = (char*)d_ws;
  size_t o = 0;
  ushort_t* x_bf = (ushort_t*)(ws + o); o += (size_t)Bn * Dn * 2;        // 4 MB
  ushort_t* w1t  = (ushort_t*)(ws + o); o += (size_t)En * Hn * Dn * 2;   // 32 MB [E][H][D]
  ushort_t* w2t  = (ushort_t*)(ws + o); o += (size_t)En * On * Hn * 2;   // 16 MB [E][O][H]
  ushort_t* hbuf = (ushort_t*)(ws + o); o += (size_t)2 * Bn * Hn * 2;    // 16 MB [slot][H]
  float* l2buf   = (float*)(ws + o);    o += (size_t)2 * Bn * On * 4;    // 8 MB  [slot][O]
  int* top_idx   = (int*)(ws + o);      o += (size_t)Bn * 2 * 4;
  float* gates   = (float*)(ws + o);    o += (size_t)Bn * 2 * 4;
  int* r2s       = (int*)(ws + o);      o += (size_t)Bn * 2 * 4;
  int* s2r       = (int*)(ws + o);      o += (size_t)2 * Bn * 4;
  int* counts    = (int*)(ws + o);      o += 64;
  int* offsets   = (int*)(ws + o);      o += 64;
  int* cursors   = (int*)(ws + o);      o += 64;

  hipLaunchKernelGGL(init_kernel, dim3(1), dim3(64), 0, stream, counts, cursors);
  hipLaunchKernelGGL(cast_x_kernel, dim3((Bn * Dn / 8 + 255) / 256), dim3(256), 0, stream,
                     x, x_bf, Bn * Dn / 8);
  hipLaunchKernelGGL(tcast_kernel, dim3(Hn / 32, Dn / 32, En), dim3(32, 8), 0, stream,
                     fc1w, w1t, Dn, Hn);
  hipLaunchKernelGGL(tcast_kernel, dim3(On / 32, Hn / 32, En), dim3(32, 8), 0, stream,
                     fc2w, w2t, Hn, On);
  hipLaunchKernelGGL(gating_kernel, dim3(Bn / 4), dim3(256), 0, stream,
                     x, wgate, top_idx, gates, counts);
  hipLaunchKernelGGL(offsets_kernel, dim3(1), dim3(64), 0, stream, counts, offsets, cursors);
  hipLaunchKernelGGL(assign_kernel, dim3(Bn / 256), dim3(256), 0, stream,
                     top_idx, offsets, cursors, s2r, r2s);
  hipLaunchKernelGGL((moe_gemm_kernel<true, true, Hn, Dn>), dim3(Hn / 128, 16, En), dim3(256), 0,
                     stream, x_bf, w1t, fc1b, offsets, counts, s2r, hbuf, (float*)nullptr);
  hipLaunchKernelGGL((moe_gemm_kernel<false, false, On, Hn>), dim3(On / 128, 16, En), dim3(256), 0,
                     stream, hbuf, w2t, fc2b, offsets, counts, s2r, (ushort_t*)nullptr, l2buf);
  hipLaunchKernelGGL(combine_kernel, dim3(Bn), dim3(256), 0, stream, l2buf, r2s, gates, out);
}

// Round 2
// 168.804 us; speedup vs baseline: 1.2834x; 1.2834x over previous
//
#include <hip/hip_runtime.h>
#include <stdint.h>

#define Bn 2048
#define Dn 1024
#define Hn 2048
#define On 512
#define En 8

typedef __bf16 bf16x8 __attribute__((ext_vector_type(8)));
typedef float f32x4 __attribute__((ext_vector_type(4)));
typedef unsigned short ushort_t;
typedef ushort_t ushort8 __attribute__((ext_vector_type(8)));

__device__ __forceinline__ ushort_t f2bf(float v) {
  union { float f; uint32_t u; } a; a.f = v;
  uint32_t u = a.u;
  return (ushort_t)((u + 0x7fffu + ((u >> 16) & 1u)) >> 16);  // RNE, finite inputs
}

__device__ __forceinline__ void gload16(const void* g, void* l) {
  __builtin_amdgcn_global_load_lds((const uint32_t*)g, (uint32_t*)l, 16, 0, 0);
}

// ---------------- init: zero counts/cursors every launch (determinism) ----------------
__global__ void init_kernel(int* counts, int* cursors) {
  int t = threadIdx.x;
  if (t < En) { counts[t] = 0; cursors[t] = 0; }
}

// ------- fused gating + x cast: 8 rows/block, wg in LDS transposed, block-agg atomics -------
__global__ __launch_bounds__(256) void gate_cast_kernel(
    const float* __restrict__ x, const float* __restrict__ wg,
    ushort_t* __restrict__ x_bf, int* __restrict__ top_idx,
    float* __restrict__ gates, int* __restrict__ counts) {
  __shared__ float wgs[En * Dn];  // [e][d], 32 KB
  __shared__ int lcnt[En];
  int t = threadIdx.x;
  for (int i = t; i < Dn * En; i += 256) {
    int d = i >> 3, e = i & 7;
    wgs[e * Dn + d] = wg[i];  // wg is [d][e]
  }
  if (t < En) lcnt[t] = 0;
  __syncthreads();
  int w = t >> 6, lane = t & 63;
#pragma unroll
  for (int r = 0; r < 2; r++) {
    int b = blockIdx.x * 8 + w * 2 + r;
    const float* xr = x + (size_t)b * Dn;
    ushort_t* xo = x_bf + (size_t)b * Dn;
    float xv[16];
#pragma unroll
    for (int j = 0; j < 16; j++) xv[j] = xr[lane + j * 64];  // 16 independent coalesced loads
    float acc[En];
#pragma unroll
    for (int e = 0; e < En; e++) acc[e] = 0.f;
#pragma unroll
    for (int j = 0; j < 16; j++) {
      int d = lane + j * 64;
      xo[d] = f2bf(xv[j]);
#pragma unroll
      for (int e = 0; e < En; e++) acc[e] += xv[j] * wgs[e * Dn + d];  // bank = lane%32: free
    }
#pragma unroll
    for (int off = 32; off; off >>= 1) {
#pragma unroll
      for (int e = 0; e < En; e++) acc[e] += __shfl_down(acc[e], off);
    }
    if (lane == 0) {
      float best = -1e30f, second = -1e30f; int bi = 0, si = 0;
#pragma unroll
      for (int e = 0; e < En; e++) {
        float l = acc[e];
        if (l > best) { second = best; si = bi; best = l; bi = e; }
        else if (l > second) { second = l; si = e; }
      }
      float e1 = expf(second - best);
      float inv = 1.f / (1.f + e1);
      top_idx[2 * b] = bi; top_idx[2 * b + 1] = si;
      gates[2 * b] = inv;  gates[2 * b + 1] = e1 * inv;
      atomicAdd(&lcnt[bi], 1);
      atomicAdd(&lcnt[si], 1);
    }
  }
  __syncthreads();
  if (t < En) {
    int c = lcnt[t];
    if (c) atomicAdd(&counts[t], c);
  }
}

// ------- transpose+cast: in [z][R][C] f32 -> out [z][C][R] bf16 (32x32 LDS tiles) -------
__global__ void tcast_kernel(const float* __restrict__ in, ushort_t* __restrict__ out, int R, int C) {
  __shared__ float tile[32][33];
  int z = blockIdx.z;
  const float* inp = in + (size_t)z * R * C;
  ushort_t* outp = out + (size_t)z * R * C;
  int r0 = blockIdx.y * 32, c0 = blockIdx.x * 32;
  int tx = threadIdx.x, ty = threadIdx.y;
#pragma unroll
  for (int j = 0; j < 32; j += 8)
    tile[ty + j][tx] = inp[(size_t)(r0 + ty + j) * C + (c0 + tx)];
  __syncthreads();
#pragma unroll
  for (int j = 0; j < 32; j += 8)
    outp[(size_t)(c0 + ty + j) * R + (r0 + tx)] = f2bf(tile[tx][ty + j]);
}

// ---------------- offsets (exclusive prefix over 8 counts) ----------------
__global__ void offsets_kernel(const int* counts, int* offsets, int* cursors) {
  if (threadIdx.x == 0) {
    int s = 0;
    for (int e = 0; e < En; e++) { offsets[e] = s; s += counts[e]; }
  }
  if (threadIdx.x < En) cursors[threadIdx.x] = 0;
}

// ---------------- assign rows to compact slots ----------------
__global__ void assign_kernel(const int* __restrict__ top_idx, const int* __restrict__ offsets,
                              int* cursors, int* __restrict__ s2r, int* __restrict__ r2s) {
  int b = blockIdx.x * 256 + threadIdx.x;
  if (b >= Bn) return;
#pragma unroll
  for (int k = 0; k < 2; k++) {
    int e = top_idx[2 * b + k];
    int pos = atomicAdd(&cursors[e], 1);
    int slot = offsets[e] + pos;
    s2r[slot] = b;
    r2s[2 * b + k] = slot;
  }
}

// ---------------- grouped GEMM: 128x128x64 tile, 4 waves, mfma 16x16x32 bf16 ----------------
template <bool GATHER, bool FC1, int N, int K>
__global__ __launch_bounds__(256, 2) void moe_gemm_kernel(
    const ushort_t* __restrict__ A, const ushort_t* __restrict__ WT,
    const float* __restrict__ bias, const int* __restrict__ offsets,
    const int* __restrict__ counts, const int* __restrict__ s2r,
    ushort_t* __restrict__ outH, float* __restrict__ outL) {
  int e = blockIdx.z;
  int cnt = counts[e];
  int rb = blockIdx.y;
  if (rb * 128 >= cnt) return;
  int base = offsets[e];
  int nb = blockIdx.x * 128;
  __shared__ __align__(16) ushort_t As[128 * 64];
  __shared__ __align__(16) ushort_t Bs[128 * 64];
  int t = threadIdx.x;
  int lane = t & 63, w = t >> 6;
  int wr = w >> 1, wc = w & 1;

  const ushort_t* aptr[4];
#pragma unroll
  for (int i = 0; i < 4; i++) {
    int lr = rb * 128 + i * 32 + (t >> 3);
    int lrc = lr < cnt ? lr : (cnt - 1);
    int slot = base + lrc;
    int row = GATHER ? s2r[slot] : slot;
    aptr[i] = A + (size_t)row * K + (t & 7) * 8;
  }
  const ushort_t* bptr = WT + ((size_t)e * N + nb + (t >> 3)) * K + (t & 7) * 8;

  f32x4 zero = {0.f, 0.f, 0.f, 0.f};
  f32x4 acc[4][4];
#pragma unroll
  for (int m = 0; m < 4; m++)
#pragma unroll
    for (int n = 0; n < 4; n++) acc[m][n] = zero;

  int arow = wr * 64 + (lane & 15);
  int brow = wc * 64 + (lane & 15);
  int kg = (lane >> 4) * 8;

  for (int kt = 0; kt < K; kt += 64) {
#pragma unroll
    for (int i = 0; i < 4; i++) {
      gload16(aptr[i] + kt, &As[i * 2048 + t * 8]);
      gload16(bptr + (size_t)i * 32 * K + kt, &Bs[i * 2048 + t * 8]);
    }
    __syncthreads();
#pragma unroll
    for (int kk = 0; kk < 64; kk += 32) {
      bf16x8 af[4], bfr[4];
#pragma unroll
      for (int m = 0; m < 4; m++) af[m] = *(const bf16x8*)&As[(arow + m * 16) * 64 + kk + kg];
#pragma unroll
      for (int n = 0; n < 4; n++) bfr[n] = *(const bf16x8*)&Bs[(brow + n * 16) * 64 + kk + kg];
#pragma unroll
      for (int m = 0; m < 4; m++)
#pragma unroll
        for (int n = 0; n < 4; n++)
          acc[m][n] = __builtin_amdgcn_mfma_f32_16x16x32_bf16(af[m], bfr[n], acc[m][n], 0, 0, 0);
    }
    __syncthreads();
  }

  int lr0 = rb * 128 + wr * 64;
#pragma unroll
  for (int m = 0; m < 4; m++) {
#pragma unroll
    for (int i = 0; i < 4; i++) {
      int lr = lr0 + m * 16 + (lane >> 4) * 4 + i;
      if (lr < cnt) {
        int slot = base + lr;
#pragma unroll
        for (int n = 0; n < 4; n++) {
          int col = nb + wc * 64 + n * 16 + (lane & 15);
          float v = acc[m][n][i] + bias[e * N + col];
          if (FC1) {
            float g = 0.5f * v * (1.0f + erff(v * 0.70710678118654752f));
            outH[(size_t)slot * N + col] = f2bf(g);
          } else {
            outL[(size_t)slot * N + col] = v;
          }
        }
      }
    }
  }
}

// ---------------- combine: per-row logsoftmax over O=512 for 2 slots, weighted sum ----------------
__device__ __forceinline__ float blk_reduce(float v, bool ismax) {
  __shared__ float sbuf[4];
  int lane = threadIdx.x & 63, w = threadIdx.x >> 6;
#pragma unroll
  for (int off = 32; off; off >>= 1) {
    float o = __shfl_down(v, off);
    v = ismax ? fmaxf(v, o) : (v + o);
  }
  __syncthreads();
  if (lane == 0) sbuf[w] = v;
  __syncthreads();
  float r = sbuf[0];
#pragma unroll
  for (int i = 1; i < 4; i++) r = ismax ? fmaxf(r, sbuf[i]) : (r + sbuf[i]);
  return r;
}

__global__ void combine_kernel(const float* __restrict__ l2, const int* __restrict__ r2s,
                               const float* __restrict__ gates, float* __restrict__ out) {
  int b = blockIdx.x, t = threadIdx.x;
  float c0 = 0.f, c1 = 0.f;
#pragma unroll
  for (int k = 0; k < 2; k++) {
    int slot = r2s[2 * b + k];
    float g = gates[2 * b + k];
    const float* lp = l2 + (size_t)slot * On;
    float v0 = lp[t], v1 = lp[t + 256];
    float m = blk_reduce(fmaxf(v0, v1), true);
    float s = blk_reduce(expf(v0 - m) + expf(v1 - m), false);
    float lse = m + logf(s);
    c0 += g * expf(v0 - lse);
    c1 += g * expf(v1 - lse);
  }
  const float EPSv = 2.220446049250313e-16f;
  out[(size_t)b * On + t] = logf(fmaxf(c0, EPSv));
  out[(size_t)b * On + t + 256] = logf(fmaxf(c1, EPSv));
}

extern "C" void kernel_launch(void* const* d_in, const int* in_sizes, int n_in,
                              void* d_out, int out_size, void* d_ws, size_t ws_size,
                              hipStream_t stream) {
  const float* x = (const float*)d_in[0];
  const float* wgate = (const float*)d_in[1];
  const float* fc1w = (const float*)d_in[2];
  const float* fc1b = (const float*)d_in[3];
  const float* fc2w = (const float*)d_in[4];
  const float* fc2b = (const float*)d_in[5];
  float* out = (float*)d_out;

  char* ws = (char*)d_ws;
  size_t o = 0;
  ushort_t* x_bf = (ushort_t*)(ws + o); o += (size_t)Bn * Dn * 2;
  ushort_t* w1t  = (ushort_t*)(ws + o); o += (size_t)En * Hn * Dn * 2;
  ushort_t* w2t  = (ushort_t*)(ws + o); o += (size_t)En * On * Hn * 2;
  ushort_t* hbuf = (ushort_t*)(ws + o); o += (size_t)2 * Bn * Hn * 2;
  float* l2buf   = (float*)(ws + o);    o += (size_t)2 * Bn * On * 4;
  int* top_idx   = (int*)(ws + o);      o += (size_t)Bn * 2 * 4;
  float* gates   = (float*)(ws + o);    o += (size_t)Bn * 2 * 4;
  int* r2s       = (int*)(ws + o);      o += (size_t)Bn * 2 * 4;
  int* s2r       = (int*)(ws + o);      o += (size_t)2 * Bn * 4;
  int* counts    = (int*)(ws + o);      o += 64;
  int* offsets   = (int*)(ws + o);      o += 64;
  int* cursors   = (int*)(ws + o);      o += 64;

  hipLaunchKernelGGL(init_kernel, dim3(1), dim3(64), 0, stream, counts, cursors);
  hipLaunchKernelGGL(gate_cast_kernel, dim3(Bn / 8), dim3(256), 0, stream,
                     x, wgate, x_bf, top_idx, gates, counts);
  hipLaunchKernelGGL(tcast_kernel, dim3(Hn / 32, Dn / 32, En), dim3(32, 8), 0, stream,
                     fc1w, w1t, Dn, Hn);
  hipLaunchKernelGGL(tcast_kernel, dim3(On / 32, Hn / 32, En), dim3(32, 8), 0, stream,
                     fc2w, w2t, Hn, On);
  hipLaunchKernelGGL(offsets_kernel, dim3(1), dim3(64), 0, stream, counts, offsets, cursors);
  hipLaunchKernelGGL(assign_kernel, dim3(Bn / 256), dim3(256), 0, stream,
                     top_idx, offsets, cursors, s2r, r2s);
  hipLaunchKernelGGL((moe_gemm_kernel<true, true, Hn, Dn>), dim3(Hn / 128, 16, En), dim3(256), 0,
                     stream, x_bf, w1t, fc1b, offsets, counts, s2r, hbuf, (float*)nullptr);
  hipLaunchKernelGGL((moe_gemm_kernel<false, false, On, Hn>), dim3(On / 128, 16, En), dim3(256), 0,
                     stream, hbuf, w2t, fc2b, offsets, counts, s2r, (ushort_t*)nullptr, l2buf);
  hipLaunchKernelGGL(combine_kernel, dim3(Bn), dim3(256), 0, stream, l2buf, r2s, gates, out);
}

// Round 4
// 158.762 us; speedup vs baseline: 1.3646x; 1.0633x over previous
//
#include <hip/hip_runtime.h>
#include <stdint.h>

#define Bn 2048
#define Dn 1024
#define Hn 2048
#define On 512
#define En 8

typedef __bf16 bf16x8 __attribute__((ext_vector_type(8)));
typedef float f32x4 __attribute__((ext_vector_type(4)));
typedef unsigned short ushort_t;
typedef ushort_t ushort8 __attribute__((ext_vector_type(8)));

__device__ __forceinline__ ushort_t f2bf(float v) {
  union { float f; uint32_t u; } a; a.f = v;
  uint32_t u = a.u;
  return (ushort_t)((u + 0x7fffu + ((u >> 16) & 1u)) >> 16);  // RNE, finite inputs
}

__device__ __forceinline__ void gload16(const void* g, void* l) {
  __builtin_amdgcn_global_load_lds((const uint32_t*)g, (uint32_t*)l, 16, 0, 0);
}

// ---------------- init: zero counts/cursors every launch (determinism) ----------------
__global__ void init_kernel(int* counts, int* cursors) {
  int t = threadIdx.x;
  if (t < En) { counts[t] = 0; cursors[t] = 0; }
}

// ------- fused gating + x cast: 8 rows/block, wg in LDS transposed, block-agg atomics -------
__global__ __launch_bounds__(256) void gate_cast_kernel(
    const float* __restrict__ x, const float* __restrict__ wg,
    ushort_t* __restrict__ x_bf, int* __restrict__ top_idx,
    float* __restrict__ gates, int* __restrict__ counts) {
  __shared__ float wgs[En * Dn];  // [e][d], 32 KB
  __shared__ int lcnt[En];
  int t = threadIdx.x;
  for (int i = t; i < Dn * En; i += 256) {
    int d = i >> 3, e = i & 7;
    wgs[e * Dn + d] = wg[i];  // wg is [d][e]
  }
  if (t < En) lcnt[t] = 0;
  __syncthreads();
  int w = t >> 6, lane = t & 63;
#pragma unroll
  for (int r = 0; r < 2; r++) {
    int b = blockIdx.x * 8 + w * 2 + r;
    const float* xr = x + (size_t)b * Dn;
    ushort_t* xo = x_bf + (size_t)b * Dn;
    float xv[16];
#pragma unroll
    for (int j = 0; j < 16; j++) xv[j] = xr[lane + j * 64];
    float acc[En];
#pragma unroll
    for (int e = 0; e < En; e++) acc[e] = 0.f;
#pragma unroll
    for (int j = 0; j < 16; j++) {
      int d = lane + j * 64;
      xo[d] = f2bf(xv[j]);
#pragma unroll
      for (int e = 0; e < En; e++) acc[e] += xv[j] * wgs[e * Dn + d];
    }
#pragma unroll
    for (int off = 32; off; off >>= 1) {
#pragma unroll
      for (int e = 0; e < En; e++) acc[e] += __shfl_down(acc[e], off);
    }
    if (lane == 0) {
      float best = -1e30f, second = -1e30f; int bi = 0, si = 0;
#pragma unroll
      for (int e = 0; e < En; e++) {
        float l = acc[e];
        if (l > best) { second = best; si = bi; best = l; bi = e; }
        else if (l > second) { second = l; si = e; }
      }
      float e1 = expf(second - best);
      float inv = 1.f / (1.f + e1);
      top_idx[2 * b] = bi; top_idx[2 * b + 1] = si;
      gates[2 * b] = inv;  gates[2 * b + 1] = e1 * inv;
      atomicAdd(&lcnt[bi], 1);
      atomicAdd(&lcnt[si], 1);
    }
  }
  __syncthreads();
  if (t < En) {
    int c = lcnt[t];
    if (c) atomicAdd(&counts[t], c);
  }
}

// ------- transpose+cast: in [z][R][C] f32 -> out [z][C][R] bf16 (32x32 LDS tiles) -------
__global__ void tcast_kernel(const float* __restrict__ in, ushort_t* __restrict__ out, int R, int C) {
  __shared__ float tile[32][33];
  int z = blockIdx.z;
  const float* inp = in + (size_t)z * R * C;
  ushort_t* outp = out + (size_t)z * R * C;
  int r0 = blockIdx.y * 32, c0 = blockIdx.x * 32;
  int tx = threadIdx.x, ty = threadIdx.y;
#pragma unroll
  for (int j = 0; j < 32; j += 8)
    tile[ty + j][tx] = inp[(size_t)(r0 + ty + j) * C + (c0 + tx)];
  __syncthreads();
#pragma unroll
  for (int j = 0; j < 32; j += 8)
    outp[(size_t)(c0 + ty + j) * R + (r0 + tx)] = f2bf(tile[tx][ty + j]);
}

// ---------------- offsets (exclusive prefix over 8 counts) ----------------
__global__ void offsets_kernel(const int* counts, int* offsets, int* cursors) {
  if (threadIdx.x == 0) {
    int s = 0;
    for (int e = 0; e < En; e++) { offsets[e] = s; s += counts[e]; }
  }
  if (threadIdx.x < En) cursors[threadIdx.x] = 0;
}

// ---------------- assign rows to compact slots ----------------
__global__ void assign_kernel(const int* __restrict__ top_idx, const int* __restrict__ offsets,
                              int* cursors, int* __restrict__ s2r, int* __restrict__ r2s) {
  int b = blockIdx.x * 256 + threadIdx.x;
  if (b >= Bn) return;
#pragma unroll
  for (int k = 0; k < 2; k++) {
    int e = top_idx[2 * b + k];
    int pos = atomicAdd(&cursors[e], 1);
    int slot = offsets[e] + pos;
    s2r[slot] = b;
    r2s[2 * b + k] = slot;
  }
}

// ---- grouped GEMM: 128x128xBK64, 4 waves, mfma 16x16x32 bf16, T2 swizzle + 2-phase dbuf ----
// LDS layout: tile[row][slot16], where slot s of row r holds global 16B-group (s ^ (r&7)).
// Staged via linear-dest global_load_lds with pre-swizzled global source (rule #21).
template <bool GATHER, bool FC1, int N, int K, int SPLITK>
__global__ __launch_bounds__(256, 2) void moe_gemm_kernel(
    const ushort_t* __restrict__ A, const ushort_t* __restrict__ WT,
    const float* __restrict__ bias, const int* __restrict__ offsets,
    const int* __restrict__ counts, const int* __restrict__ s2r,
    ushort_t* __restrict__ outH, float* __restrict__ outL, float* __restrict__ outL2) {
  constexpr int NBL = N / 128;
  constexpr int KS = K / SPLITK;
  constexpr int NT = KS / 64;
  int e = blockIdx.z;
  int cnt = counts[e];
  int rb = blockIdx.y;
  if (rb * 128 >= cnt) return;
  int base = offsets[e];
  int ks = blockIdx.x / NBL;
  int nb = (blockIdx.x % NBL) * 128;
  int k0 = ks * KS;
  __shared__ __align__(16) ushort_t As[2][128 * 64];
  __shared__ __align__(16) ushort_t Bs[2][128 * 64];
  int t = threadIdx.x;
  int lane = t & 63, w = t >> 6;
  int wr = w >> 1, wc = w & 1;

  int srow = t >> 3;                       // staging row within each 32-row group
  int scol = ((t & 7) ^ (srow & 7)) * 8;   // pre-swizzled global column (elements)

  const ushort_t* aptr[4];
#pragma unroll
  for (int i = 0; i < 4; i++) {
    int lr = rb * 128 + i * 32 + srow;
    int lrc = lr < cnt ? lr : cnt - 1;
    int slot = base + lrc;
    int row = GATHER ? s2r[slot] : slot;
    aptr[i] = A + (size_t)row * K + k0 + scol;
  }
  const ushort_t* bptr = WT + ((size_t)e * N + nb + srow) * K + k0 + scol;

  f32x4 zero = {0.f, 0.f, 0.f, 0.f};
  f32x4 acc[4][4];
#pragma unroll
  for (int m = 0; m < 4; m++)
#pragma unroll
    for (int n = 0; n < 4; n++) acc[m][n] = zero;

  int a_r = wr * 64 + (lane & 15);   // A fragment row base
  int b_r = wc * 64 + (lane & 15);   // B fragment row base
  int axor = lane & 7;               // row&7 (row base is mult of 8 -> invariant)
  int c16 = lane >> 4;               // base 16B-slot index within row

#define STAGE(buf, kt)                                              \
  {                                                                 \
    _Pragma("unroll") for (int i = 0; i < 4; i++) {                 \
      gload16(aptr[i] + (kt) * 64, &As[buf][i * 2048 + t * 8]);     \
      gload16(bptr + (size_t)i * 32 * K + (kt) * 64,                \
              &Bs[buf][i * 2048 + t * 8]);                          \
    }                                                               \
  }

#define COMPUTE(buf)                                                          \
  {                                                                           \
    _Pragma("unroll") for (int kk = 0; kk < 2; kk++) {                        \
      bf16x8 af[4], bfr[4];                                                   \
      _Pragma("unroll") for (int m = 0; m < 4; m++)                           \
          af[m] = *(const bf16x8*)((const char*)&As[buf][0] +                 \
                                   (a_r + m * 16) * 128 +                     \
                                   (((kk * 4 + c16) ^ axor) << 4));           \
      _Pragma("unroll") for (int n = 0; n < 4; n++)                           \
          bfr[n] = *(const bf16x8*)((const char*)&Bs[buf][0] +                \
                                    (b_r + n * 16) * 128 +                    \
                                    (((kk * 4 + c16) ^ axor) << 4));          \
      _Pragma("unroll") for (int m = 0; m < 4; m++)                           \
          _Pragma("unroll") for (int n = 0; n < 4; n++)                       \
              acc[m][n] = __builtin_amdgcn_mfma_f32_16x16x32_bf16(            \
                  af[m], bfr[n], acc[m][n], 0, 0, 0);                         \
    }                                                                         \
  }

  // 2-phase pipeline: issue next-tile loads before computing current tile.
  STAGE(0, 0);
  __syncthreads();
  int cur = 0;
#pragma unroll 2
  for (int kt = 1; kt < NT; kt++) {
    STAGE(cur ^ 1, kt);
    COMPUTE(cur);
    __syncthreads();
    cur ^= 1;
  }
  COMPUTE(cur);
#undef STAGE
#undef COMPUTE

  // epilogue: D layout col=lane&15, row=(lane>>4)*4+i
  float* dst = (SPLITK > 1 && ks == 1) ? outL2 : outL;
  int lr0 = rb * 128 + wr * 64;
#pragma unroll
  for (int m = 0; m < 4; m++) {
#pragma unroll
    for (int i = 0; i < 4; i++) {
      int lr = lr0 + m * 16 + (lane >> 4) * 4 + i;
      if (lr < cnt) {
        int slot = base + lr;
#pragma unroll
        for (int n = 0; n < 4; n++) {
          int col = nb + wc * 64 + n * 16 + (lane & 15);
          float v = acc[m][n][i] + (ks == 0 ? bias[e * N + col] : 0.f);
          if (FC1) {
            float g = 0.5f * v * (1.0f + erff(v * 0.70710678118654752f));
            outH[(size_t)slot * N + col] = f2bf(g);
          } else {
            dst[(size_t)slot * N + col] = v;
          }
        }
      }
    }
  }
}

// ---------------- combine: sum split-K partials, logsoftmax over O=512, weighted sum ----------------
__device__ __forceinline__ float blk_reduce(float v, bool ismax) {
  __shared__ float sbuf[4];
  int lane = threadIdx.x & 63, w = threadIdx.x >> 6;
#pragma unroll
  for (int off = 32; off; off >>= 1) {
    float o = __shfl_down(v, off);
    v = ismax ? fmaxf(v, o) : (v + o);
  }
  __syncthreads();
  if (lane == 0) sbuf[w] = v;
  __syncthreads();
  float r = sbuf[0];
#pragma unroll
  for (int i = 1; i < 4; i++) r = ismax ? fmaxf(r, sbuf[i]) : (r + sbuf[i]);
  return r;
}

__global__ void combine_kernel(const float* __restrict__ l2a, const float* __restrict__ l2b,
                               const int* __restrict__ r2s, const float* __restrict__ gates,
                               float* __restrict__ out) {
  int b = blockIdx.x, t = threadIdx.x;
  float c0 = 0.f, c1 = 0.f;
#pragma unroll
  for (int k = 0; k < 2; k++) {
    int slot = r2s[2 * b + k];
    float g = gates[2 * b + k];
    const float* lp0 = l2a + (size_t)slot * On;
    const float* lp1 = l2b + (size_t)slot * On;
    float v0 = lp0[t] + lp1[t];
    float v1 = lp0[t + 256] + lp1[t + 256];
    float m = blk_reduce(fmaxf(v0, v1), true);
    float s = blk_reduce(expf(v0 - m) + expf(v1 - m), false);
    float lse = m + logf(s);
    c0 += g * expf(v0 - lse);
    c1 += g * expf(v1 - lse);
  }
  const float EPSv = 2.220446049250313e-16f;
  out[(size_t)b * On + t] = logf(fmaxf(c0, EPSv));
  out[(size_t)b * On + t + 256] = logf(fmaxf(c1, EPSv));
}

extern "C" void kernel_launch(void* const* d_in, const int* in_sizes, int n_in,
                              void* d_out, int out_size, void* d_ws, size_t ws_size,
                              hipStream_t stream) {
  const float* x = (const float*)d_in[0];
  const float* wgate = (const float*)d_in[1];
  const float* fc1w = (const float*)d_in[2];
  const float* fc1b = (const float*)d_in[3];
  const float* fc2w = (const float*)d_in[4];
  const float* fc2b = (const float*)d_in[5];
  float* out = (float*)d_out;

  char* ws = (char*)d_ws;
  size_t o = 0;
  ushort_t* x_bf = (ushort_t*)(ws + o); o += (size_t)Bn * Dn * 2;        // 4 MB
  ushort_t* w1t  = (ushort_t*)(ws + o); o += (size_t)En * Hn * Dn * 2;   // 32 MB [E][H][D]
  ushort_t* w2t  = (ushort_t*)(ws + o); o += (size_t)En * On * Hn * 2;   // 16 MB [E][O][H]
  ushort_t* hbuf = (ushort_t*)(ws + o); o += (size_t)2 * Bn * Hn * 2;    // 16 MB [slot][H]
  float* l2buf   = (float*)(ws + o);    o += (size_t)2 * Bn * On * 4;    // 8 MB (split-K partial 0)
  int* top_idx   = (int*)(ws + o);      o += (size_t)Bn * 2 * 4;
  float* gates   = (float*)(ws + o);    o += (size_t)Bn * 2 * 4;
  int* r2s       = (int*)(ws + o);      o += (size_t)Bn * 2 * 4;
  int* s2r       = (int*)(ws + o);      o += (size_t)2 * Bn * 4;
  int* counts    = (int*)(ws + o);      o += 64;
  int* offsets   = (int*)(ws + o);      o += 64;
  int* cursors   = (int*)(ws + o);      o += 64;
  // split-K partial 1 (8 MB) aliases w1t: w1t is fully consumed by fc1 (which completes
  // before fc2 starts on the same stream) and fully rewritten by tcast each launch.
  float* l2buf1  = (float*)w1t;

  hipLaunchKernelGGL(init_kernel, dim3(1), dim3(64), 0, stream, counts, cursors);
  hipLaunchKernelGGL(gate_cast_kernel, dim3(Bn / 8), dim3(256), 0, stream,
                     x, wgate, x_bf, top_idx, gates, counts);
  hipLaunchKernelGGL(tcast_kernel, dim3(Hn / 32, Dn / 32, En), dim3(32, 8), 0, stream,
                     fc1w, w1t, Dn, Hn);
  hipLaunchKernelGGL(tcast_kernel, dim3(On / 32, Hn / 32, En), dim3(32, 8), 0, stream,
                     fc2w, w2t, Hn, On);
  hipLaunchKernelGGL(offsets_kernel, dim3(1), dim3(64), 0, stream, counts, offsets, cursors);
  hipLaunchKernelGGL(assign_kernel, dim3(Bn / 256), dim3(256), 0, stream,
                     top_idx, offsets, cursors, s2r, r2s);
  hipLaunchKernelGGL((moe_gemm_kernel<true, true, Hn, Dn, 1>), dim3(Hn / 128, 16, En), dim3(256),
                     0, stream, x_bf, w1t, fc1b, offsets, counts, s2r, hbuf, (float*)nullptr,
                     (float*)nullptr);
  hipLaunchKernelGGL((moe_gemm_kernel<false, false, On, Hn, 2>), dim3((On / 128) * 2, 16, En),
                     dim3(256), 0, stream, hbuf, w2t, fc2b, offsets, counts, s2r,
                     (ushort_t*)nullptr, l2buf, l2buf1);
  hipLaunchKernelGGL(combine_kernel, dim3(Bn), dim3(256), 0, stream, l2buf, l2buf1, r2s, gates, out);
}